// Round 12
// baseline (48.622 us; speedup 1.0000x reference)
//
#include <hip/hip_runtime.h>
#include <math.h>

#define NEAR_T   2.0f
#define FAR_T    6.0f
#define EPS_W_C  1e-5f
#define EPS_T_C  1e-10f
#define FAR_DIST 1e10f
#define L2E      1.4426950408889634f
#define INV63    (1.0f / 63.0f)

typedef float v2f __attribute__((ext_vector_type(2)));

__device__ __forceinline__ float tval(int i) {
    return NEAR_T + (FAR_T - NEAR_T) * ((float)i * INV63);
}
__device__ __forceinline__ float rcp_fast(float x) { return __builtin_amdgcn_rcpf(x); }
__device__ __forceinline__ float exp2_f(float x)  { return __builtin_amdgcn_exp2f(x); }
__device__ __forceinline__ float log2_f(float x)  { return __builtin_amdgcn_logf(x); }
__device__ __forceinline__ v2f fma2(v2f a, v2f b, v2f c) {
    return __builtin_elementwise_fma(a, b, c);
}

// safe base-2 softplus (two-path log2(1+e)): preserves sigma down to ~1e-13,
// REQUIRED where dist=1e10 can saturate alpha from a tiny sigma (R2 failure).
__device__ __forceinline__ float softplus2_safe(float xp) {
    const float e = exp2_f(-fabsf(xp));
    const float big   = log2_f(1.0f + e);
    const float small = e * (1.4426950f - e * (0.72134751f - e * 0.48089835f));
    return fmaxf(xp, 0.0f) + ((e > 0.0078125f) ? big : small);
}

struct FieldV { float sig; float c2; v2f c01; };

// fast field eval: softplus without the small path (flushes sigma < 2^-24 to 0;
// alpha error < 2^-24*4 for bounded dists — only FAR_DIST consumers need the
// safe version). Pairable math packed for v_pk_fma/v_pk_add.
__device__ __forceinline__ FieldV eval_fast(float t, v2f A0, v2f A1, v2f B0, v2f B1) {
    const v2f tt = {t, t};
    const v2f a = fma2(tt, A1, A0);          // (dd', c2-arg)
    const v2f b = fma2(tt, B1, B0);          // (c0-arg, c1-arg)
    const float ea  = exp2_f(-fabsf(a.x));
    const float ec  = exp2_f(-a.y);
    const float eb0 = exp2_f(-b.x);
    const float eb1 = exp2_f(-b.y);
    const v2f pa = (v2f){ea, ec} + (v2f){1.0f, 1.0f};
    const v2f pb = (v2f){eb0, eb1} + (v2f){1.0f, 1.0f};
    FieldV r;
    r.sig = fmaxf(a.x, 0.0f) + log2_f(pa.x);
    r.c2  = rcp_fast(pa.y);
    r.c01 = (v2f){rcp_fast(pb.x), rcp_fast(pb.y)};
    return r;
}

__global__ __launch_bounds__(256)
void volrender_tpr(const float* __restrict__ ro_g,
                   const float* __restrict__ rd_g,
                   const float* __restrict__ Wd_g,
                   const float* __restrict__ Wc_g,
                   float* __restrict__ out, int N) {
    __shared__ float s_cdf[64][256];   // [i][tid]: banks = tid%32, conflict-free

    const int tid = threadIdx.x;
    const int ray = blockIdx.x * 256 + tid;
    if (ray >= N) return;

    const float ox = ro_g[ray * 3 + 0], oy = ro_g[ray * 3 + 1], oz = ro_g[ray * 3 + 2];
    const float dx = rd_g[ray * 3 + 0], dy = rd_g[ray * 3 + 1], dz = rd_g[ray * 3 + 2];
    const float wd0 = Wd_g[0], wd1 = Wd_g[1], wd2 = Wd_g[2];
    float wcm[9];
#pragma unroll
    for (int k = 0; k < 9; ++k) wcm[k] = Wc_g[k];

    // affine-in-t field coefficients, pre-scaled by log2e; packed as
    // A = (density, color2), B = (color0, color1)
    const v2f A0 = { (ox * wd0 + oy * wd1 + oz * wd2) * L2E,
                     (ox * wcm[2] + oy * wcm[5] + oz * wcm[8]) * L2E };
    const v2f A1 = { (dx * wd0 + dy * wd1 + dz * wd2) * L2E,
                     (dx * wcm[2] + dy * wcm[5] + dz * wcm[8]) * L2E };
    const v2f B0 = { (ox * wcm[0] + oy * wcm[3] + oz * wcm[6]) * L2E,
                     (ox * wcm[1] + oy * wcm[4] + oz * wcm[7]) * L2E };
    const v2f B1 = { (dx * wcm[0] + dy * wcm[3] + dz * wcm[6]) * L2E,
                     (dx * wcm[1] + dy * wcm[4] + dz * wcm[7]) * L2E };

    const float W = (FAR_T - NEAR_T) * INV63;
    const float TMAX = tval(63);

    const long Nl = N;
    float* out_rgb  = out;
    float* out_dep  = out + 3 * Nl;
    float* out_acc  = out + 4 * Nl;
    float* out_frgb = out + 5 * Nl;
    float* out_fdep = out + 8 * Nl;
    float* out_facc = out + 9 * Nl;

    // ---------------- pass 1: coarse march + cdf store ----------------
    float trans = 1.0f, r2 = 0.0f, total = 0.0f;
    v2f accdep = {0.0f, 0.0f};          // (acc, dep) packed
    v2f r01 = {0.0f, 0.0f};
    float t = NEAR_T;
#pragma unroll 4
    for (int i = 0; i < 63; ++i) {
        const FieldV F = eval_fast(t, A0, A1, B0, B1);
        const float a = 1.0f - exp2_f(-F.sig * W);
        const float w = a * trans;
        trans *= (1.0f - a + EPS_T_C);
        accdep = fma2((v2f){w, w}, (v2f){1.0f, t}, accdep);
        r01 = fma2((v2f){w, w}, F.c01, r01);
        r2 = fmaf(w, F.c2, r2);
        total += w + EPS_W_C;
        s_cdf[i][tid] = total;
        t += W;
    }
    {   // i = 63: dist = FAR_DIST -> needs safe softplus
        FieldV F = eval_fast(t, A0, A1, B0, B1);
        const float sig = softplus2_safe(fmaf(t, A1.x, A0.x));
        const float a = 1.0f - exp2_f(-sig * FAR_DIST);
        const float w = a * trans;
        accdep = fma2((v2f){w, w}, (v2f){1.0f, t}, accdep);
        r01 = fma2((v2f){w, w}, F.c01, r01);
        r2 = fmaf(w, F.c2, r2);
        total += w + EPS_W_C;
        s_cdf[63][tid] = total;
    }
    {
        const float bg = 1.0f - accdep.x;
        out_rgb[ray * 3 + 0] = r01.x + bg;
        out_rgb[ray * 3 + 1] = r01.y + bg;
        out_rgb[ray * 3 + 2] = r2 + bg;
        out_dep[ray] = accdep.y;
        out_acc[ray] = accdep.x;
    }
    const float inv_total = rcp_fast(total);

    // ---------------- pass 2: fused sample + merge + fine ----------------
    float transf = 1.0f, fr2 = 0.0f;
    v2f faccdep = {0.0f, 0.0f};
    v2f fr01 = {0.0f, 0.0f};
    float lo, hi, bin0, bin1, tscale;
    int i, j = 0;
    float u = 0.0f;                         // = j/63, incremental
    float pt, ps, pc2;                      // lagged previous merged element
    v2f pc01;
    float Sn1, Sn2;                         // depth-2 cdf prefetch

    {   // peel e=0: always grid 0
        const FieldV F = eval_fast(NEAR_T, A0, A1, B0, B1);
        ps = F.sig; pc01 = F.c01; pc2 = F.c2; pt = NEAR_T;
        lo = 0.0f;
        hi = s_cdf[0][tid] * inv_total;
        bin0 = NEAR_T; bin1 = NEAR_T + W;
        const float dnm = hi;               // hi - lo
        const float binw = bin1 - bin0;
        tscale = (dnm < EPS_W_C) ? binw : binw * rcp_fast(dnm);
        i = 1;
        Sn1 = s_cdf[1][tid];
        Sn2 = s_cdf[2][tid];
    }

#pragma unroll 4
    for (int e = 1; e < 128; ++e) {
        // importance-sample candidate from head u (rcp hoisted into tscale)
        const float ts = fmaf(u - lo, tscale, bin0);
        const bool samp = (j < 64) && ((i >= 64) || (u < hi));
        const float tm = samp ? ts : bin1;

        const FieldV F = eval_fast(tm, A0, A1, B0, B1);

        // fine composite of PREVIOUS element with dist = tm - pt
        const float af = 1.0f - exp2_f(-ps * (tm - pt));
        const float wf = af * transf;
        transf *= (1.0f - af + EPS_T_C);
        faccdep = fma2((v2f){wf, wf}, (v2f){1.0f, pt}, faccdep);
        fr01 = fma2((v2f){wf, wf}, pc01, fr01);
        fr2 = fmaf(wf, pc2, fr2);

        if (samp) {
            ++j; u += INV63;
        } else {
            lo = hi;
            hi = Sn1 * inv_total;           // prefetched >=1 iter ago
            Sn1 = Sn2;
            bin0 = bin1;
            bin1 = fminf(bin1 + W, TMAX);
            const float dnm = hi - lo;
            const float binw = bin1 - bin0;
            tscale = (dnm < EPS_W_C) ? binw : binw * rcp_fast(dnm);
            ++i;
            Sn2 = s_cdf[min(i + 1, 63)][tid];
        }
        pt = tm; ps = F.sig; pc01 = F.c01; pc2 = F.c2;
    }

    {   // epilogue: last merged element gets FAR_DIST -> safe sigma recompute
        const float sig = softplus2_safe(fmaf(pt, A1.x, A0.x));
        const float af = 1.0f - exp2_f(-sig * FAR_DIST);
        const float wf = af * transf;
        faccdep = fma2((v2f){wf, wf}, (v2f){1.0f, pt}, faccdep);
        fr01 = fma2((v2f){wf, wf}, pc01, fr01);
        fr2 = fmaf(wf, pc2, fr2);

        const float bg = 1.0f - faccdep.x;
        out_frgb[ray * 3 + 0] = fr01.x + bg;
        out_frgb[ray * 3 + 1] = fr01.y + bg;
        out_frgb[ray * 3 + 2] = fr2 + bg;
        out_fdep[ray] = faccdep.y;
        out_facc[ray] = faccdep.x;
    }
}

extern "C" void kernel_launch(void* const* d_in, const int* in_sizes, int n_in,
                              void* d_out, int out_size, void* d_ws, size_t ws_size,
                              hipStream_t stream) {
    const float* ro = (const float*)d_in[0];
    const float* rd = (const float*)d_in[1];
    // d_in[2] exposure_values, d_in[5] appearance_ids: unused by reference
    const float* Wd = (const float*)d_in[3];
    const float* Wc = (const float*)d_in[4];
    float* out = (float*)d_out;

    const int N = in_sizes[0] / 3;
    const int grid = (N + 255) / 256;
    volrender_tpr<<<grid, 256, 0, stream>>>(ro, rd, Wd, Wc, out, N);
}